// Round 11
// baseline (1077.780 us; speedup 1.0000x reference)
//
#include <hip/hip_runtime.h>

#define EMBD 300
#define NSTEP 300
#define HID 512
#define G4 2048
#define TPB1 256
#define TPB2 320            // 4 compute waves + 1 publisher wave
#define NCLUST 8
#define NMEMB 32            // WGs per cluster (one XCD's worth of CUs)

#define TS2 15              // steps per phase-1 step-group
#define NSG 20              // step groups (20*15 = 300)
#define NRG 8               // row groups (8*256 = 2048 rows)

#define SENTINEL 0xFFC00000u   // quiet NaN: h values are always finite

// ws float layout:
//   [0 .. 614400)      : X_proj [300][2048]
//   [614400 .. +154112): HSEQ [301][512]  (shared by all clusters; same-value
//                        multi-writer races are benign, slots are word-atomic)
#define XP_SZ    (NSTEP * G4)
#define HSEQ_OFF XP_SZ

__device__ __forceinline__ float fsig(float x) { return 1.0f / (1.0f + __expf(-x)); }
__device__ __forceinline__ float ftanh(float x) {
    x = fminf(15.0f, fmaxf(-15.0f, x));
    float t = __expf(2.0f * x);
    return (t - 1.0f) / (t + 1.0f);
}

// L1-bypass load/store: served by the CU's XCD-shared L2 (fast ack / fast hit
// when producer+consumer share an XCD). NO "memory" clobber: the poll value
// feeds consumers by dataflow, and leaving LDS unclobbered lets the compiler
// keep/hoist LDS weight reads freely.
__device__ __forceinline__ unsigned long long load2_sc0(const void* p) {
    unsigned long long v;
    asm volatile("global_load_dwordx2 %0, %1, off sc0\n\ts_waitcnt vmcnt(0)"
                 : "=v"(v) : "v"(p));
    return v;
}
__device__ __forceinline__ void store1_sc0(void* p, unsigned v) {
    asm volatile("global_store_dword %0, %1, off sc0" :: "v"(p), "v"(v));
}

// Phase 1: X_proj[t][r] = b_ih[r]+b_hh[r] + sum_e W_ih[r][e]*emb[x[t]][e]
// Grid (NRG, NSG). rowg==0 blocks sentinel-clear HSEQ rows t0+1..t0+15;
// (0,0) also copies h0 into HSEQ[0]. Re-done every call -> replay-safe.
__global__ __launch_bounds__(TPB1) void xproj_init_kernel(
    const int* __restrict__ x, const float* __restrict__ h0,
    const float* __restrict__ emb, const float* __restrict__ W_ih,
    const float* __restrict__ b_ih, const float* __restrict__ b_hh,
    float* __restrict__ ws) {
    const int rowg = blockIdx.x;      // 0..7
    const int sg   = blockIdx.y;      // 0..19
    const int tid  = threadIdx.x;
    const int t0   = sg * TS2;
    const int r    = rowg * TPB1 + tid;

    float* hseq = ws + HSEQ_OFF;

    if (rowg == 0) {
        unsigned* hs = (unsigned*)(hseq + (size_t)(t0 + 1) * HID);
        for (int i = tid; i < TS2 * HID; i += TPB1) hs[i] = SENTINEL;
        if (sg == 0) {
            for (int i = tid; i < HID; i += TPB1) hseq[i] = h0[i];
        }
    }

    __shared__ float e_lds[TS2][EMBD];
    for (int tt = 0; tt < TS2; ++tt) {
        const float* er = emb + (long long)x[t0 + tt] * EMBD;
        for (int i = tid; i < EMBD; i += TPB1) e_lds[tt][i] = er[i];
    }
    __syncthreads();

    float acc[TS2];
    const float bsum = b_ih[r] + b_hh[r];
    #pragma unroll
    for (int tt = 0; tt < TS2; ++tt) acc[tt] = bsum;

    const float* wrow = W_ih + (size_t)r * EMBD;
    for (int e = 0; e < EMBD; e += 4) {
        const float4 w4 = *(const float4*)(wrow + e);
        #pragma unroll
        for (int tt = 0; tt < TS2; ++tt) {
            acc[tt] = fmaf(w4.x, e_lds[tt][e],     acc[tt]);
            acc[tt] = fmaf(w4.y, e_lds[tt][e + 1], acc[tt]);
            acc[tt] = fmaf(w4.z, e_lds[tt][e + 2], acc[tt]);
            acc[tt] = fmaf(w4.w, e_lds[tt][e + 3], acc[tt]);
        }
    }
    #pragma unroll
    for (int tt = 0; tt < TS2; ++tt)
        ws[(size_t)(t0 + tt) * G4 + r] = acc[tt];
}

// Phase 2: 256 WGs = 8 redundant clusters x 32 members. Cluster = wg%8
// (round-robin dispatch => one XCD per cluster; 137KB LDS forces 1 WG/CU so
// all 256 CUs are covered). Each cluster computes the FULL scan; exchange is
// intra-cluster sc0 stores/polls through the XCD-local L2. Wave 4 is a
// dedicated agent-scope re-publisher (its slow store-acks are never drained
// by polling waves); every 16th consumer poll is an agent-scope load ->
// mixed-XCD placement degrades gracefully instead of hanging.
// W_hh slice lives in LDS (128KB): wlds[hidx4][gate][k4][li][4].
__global__ __launch_bounds__(TPB2, 1) void lstm_scan_kernel(
    const float* __restrict__ c0, const float* __restrict__ W_hh,
    const float* __restrict__ fc_w, const float* __restrict__ fc_b,
    float* __restrict__ ws, float* __restrict__ out) {
    const int tid  = threadIdx.x;
    const int wgid = blockIdx.x;
    const int m    = wgid >> 3;    // member 0..31 (plays the old 'wg' role)
    const int v    = tid >> 6;     // wave id (0..4; 4 = publisher)
    const int lane = tid & 63;
    const int g    = lane >> 4;    // group within wave
    const int li   = lane & 15;    // lane within group (column split)
    const int hidx4 = v * 4 + g;   // local h index 0..15 (for v<4)
    const int hidx  = m * 16 + hidx4;

    float* hseq     = ws + HSEQ_OFF;        // [301][512]
    const float* xp = ws;                   // [300][2048]

    __shared__ __align__(16) float wlds[16 * 4 * 8 * 16 * 4];  // 128 KiB
    __shared__ __align__(16) float h_lds[2][576];  // idx i -> i + 4*(i>>5)
    __shared__ float hpub[16];
    __shared__ float red[256];

    // Stage this member's W_hh slice into LDS (one-time).
    if (v < 4) {
        #pragma unroll
        for (int gate = 0; gate < 4; ++gate) {
            const float* wr = W_hh + ((size_t)gate * HID + hidx) * HID + li * 32;
            #pragma unroll
            for (int k4 = 0; k4 < 8; ++k4) {
                *(float4*)&wlds[((((hidx4 * 4) + gate) * 8 + k4) * 16 + li) * 4] =
                    *(const float4*)(wr + k4 * 4);
            }
        }
    }
    __syncthreads();

    const bool upd = (v < 4) && (li == 0);
    float c = upd ? c0[hidx] : 0.0f;

    for (int s = 0; s < NSTEP; ++s) {
        if (v < 4) {
            // X_proj loads issued before the poll -> latency hidden under it.
            float xi = 0.f, xf = 0.f, xg = 0.f, xo = 0.f;
            if (upd) {
                const float* xpt = xp + (size_t)s * G4 + hidx;
                xi = xpt[0]; xf = xpt[HID]; xg = xpt[2 * HID]; xo = xpt[3 * HID];
            }

            // Poll own 8B slot of HSEQ[s]: sc0 fast path (XCD-local L2 hit),
            // every 16th iteration agent-scope fallback (guaranteed progress).
            {
                const unsigned long long* slot =
                    (const unsigned long long*)(hseq + (size_t)s * HID) + tid;
                unsigned long long hv = load2_sc0(slot);
                int k = 0;
                while ((unsigned)hv == SENTINEL || (unsigned)(hv >> 32) == SENTINEL) {
                    if ((++k & 15) == 0)
                        hv = __hip_atomic_load(slot, __ATOMIC_RELAXED,
                                               __HIP_MEMORY_SCOPE_AGENT);
                    else
                        hv = load2_sc0(slot);
                }
                const int i0 = 2 * tid;
                *(float2*)&h_lds[s & 1][i0 + ((i0 >> 5) << 2)] =
                    make_float2(__uint_as_float((unsigned)hv),
                                __uint_as_float((unsigned)(hv >> 32)));
            }
            asm volatile("s_waitcnt lgkmcnt(0)");
            __builtin_amdgcn_s_barrier();      // A: fill -> compute (no vm drain)

            // h chunk into registers once; k-outer, gate-inner over LDS weights.
            float4 hreg[8];
            const float* hrow = &h_lds[s & 1][li * 36];
            #pragma unroll
            for (int k4 = 0; k4 < 8; ++k4) hreg[k4] = *(const float4*)(hrow + k4 * 4);

            float a0 = 0.f, a1 = 0.f, a2 = 0.f, a3 = 0.f;
            #pragma unroll
            for (int k4 = 0; k4 < 8; ++k4) {
                const float4 h4 = hreg[k4];
                const float4 w0 = *(const float4*)&wlds[(((hidx4 * 4 + 0) * 8 + k4) * 16 + li) * 4];
                const float4 w1 = *(const float4*)&wlds[(((hidx4 * 4 + 1) * 8 + k4) * 16 + li) * 4];
                const float4 w2 = *(const float4*)&wlds[(((hidx4 * 4 + 2) * 8 + k4) * 16 + li) * 4];
                const float4 w3 = *(const float4*)&wlds[(((hidx4 * 4 + 3) * 8 + k4) * 16 + li) * 4];
                a0 = fmaf(w0.x, h4.x, a0); a0 = fmaf(w0.y, h4.y, a0);
                a0 = fmaf(w0.z, h4.z, a0); a0 = fmaf(w0.w, h4.w, a0);
                a1 = fmaf(w1.x, h4.x, a1); a1 = fmaf(w1.y, h4.y, a1);
                a1 = fmaf(w1.z, h4.z, a1); a1 = fmaf(w1.w, h4.w, a1);
                a2 = fmaf(w2.x, h4.x, a2); a2 = fmaf(w2.y, h4.y, a2);
                a2 = fmaf(w2.z, h4.z, a2); a2 = fmaf(w2.w, h4.w, a2);
                a3 = fmaf(w3.x, h4.x, a3); a3 = fmaf(w3.y, h4.y, a3);
                a3 = fmaf(w3.z, h4.z, a3); a3 = fmaf(w3.w, h4.w, a3);
            }
            #define RED16(A) A += __shfl_xor(A, 1); A += __shfl_xor(A, 2); \
                             A += __shfl_xor(A, 4); A += __shfl_xor(A, 8);
            RED16(a0) RED16(a1) RED16(a2) RED16(a3)
            #undef RED16

            if (upd) {
                const float iv = fsig(a0 + xi);
                const float fv = fsig(a1 + xf);
                const float gv = ftanh(a2 + xg);
                const float ov = fsig(a3 + xo);
                c = fv * c + iv * gv;
                const float h = ov * ftanh(c);
                // Fast local publish (XCD L2) + stash for the publisher wave.
                store1_sc0((unsigned*)(hseq + (size_t)(s + 1) * HID + hidx),
                           __float_as_uint(h));
                hpub[hidx4] = h;
                if (s == NSTEP - 1) {
                    out[1 + hidx] = h;
                    out[1 + HID + hidx] = c;
                }
            }
            asm volatile("s_waitcnt lgkmcnt(0)");
            __builtin_amdgcn_s_barrier();      // B: hpub ready for wave 4
        } else {
            // Publisher wave: mirror barriers A and B, then re-publish the 16
            // new h values at agent scope (slow acks stay in THIS wave only).
            __builtin_amdgcn_s_barrier();      // A
            __builtin_amdgcn_s_barrier();      // B
            if (lane < 16) {
                const float h = hpub[lane];
                __hip_atomic_store((unsigned*)(hseq + (size_t)(s + 1) * HID + m * 16 + lane),
                                   __float_as_uint(h),
                                   __ATOMIC_RELAXED, __HIP_MEMORY_SCOPE_AGENT);
            }
        }
    }

    // Epilogue: member 0 of every cluster computes out[0] (idempotent).
    if (m == 0) {
        if (tid < 256) {
            const unsigned long long* slot =
                (const unsigned long long*)(hseq + (size_t)NSTEP * HID) + tid;
            unsigned long long hv = load2_sc0(slot);
            int k = 0;
            while ((unsigned)hv == SENTINEL || (unsigned)(hv >> 32) == SENTINEL) {
                if ((++k & 15) == 0)
                    hv = __hip_atomic_load(slot, __ATOMIC_RELAXED,
                                           __HIP_MEMORY_SCOPE_AGENT);
                else
                    hv = load2_sc0(slot);
            }
            red[tid] = __uint_as_float((unsigned)hv) * fc_w[2 * tid]
                     + __uint_as_float((unsigned)(hv >> 32)) * fc_w[2 * tid + 1];
        }
        __syncthreads();
        for (int off = 128; off > 0; off >>= 1) {
            if (tid < off) red[tid] += red[tid + off];
            __syncthreads();
        }
        if (tid == 0) out[0] = fsig(red[0] + fc_b[0]);
    }
}

extern "C" void kernel_launch(void* const* d_in, const int* in_sizes, int n_in,
                              void* d_out, int out_size, void* d_ws, size_t ws_size,
                              hipStream_t stream) {
    (void)in_sizes; (void)n_in; (void)out_size; (void)ws_size;
    const int*   x     = (const int*)d_in[0];
    const float* h0    = (const float*)d_in[1];
    const float* c0    = (const float*)d_in[2];
    const float* emb   = (const float*)d_in[3];
    const float* W_ih  = (const float*)d_in[4];
    const float* W_hh  = (const float*)d_in[5];
    const float* b_ih  = (const float*)d_in[6];
    const float* b_hh  = (const float*)d_in[7];
    const float* fc_w  = (const float*)d_in[8];
    const float* fc_b  = (const float*)d_in[9];
    float* out = (float*)d_out;
    float* ws  = (float*)d_ws;

    xproj_init_kernel<<<dim3(NRG, NSG), dim3(TPB1), 0, stream>>>(
        x, h0, emb, W_ih, b_ih, b_hh, ws);
    lstm_scan_kernel<<<dim3(NCLUST * NMEMB), dim3(TPB2), 0, stream>>>(
        c0, W_hh, fc_w, fc_b, ws, out);
}